// Round 13
// baseline (11370.259 us; speedup 1.0000x reference)
//
#include <hip/hip_runtime.h>
#include <math.h>

// TD3ActorDSNN — f32 class-faithful, fused, round 13.
// Exactness invariants (validated r4-r6, r9, r11, r12):
//  - per-element k-ascending single-accumulator f32 chains for h0 and h1;
//    skipping k with mask==0 is bit-identical; order never changes.
//  - b in {0,1}: fma(b,w,acc) EXACT (b=1 -> RN(acc+w) == validated add;
//    b=0 -> acc unchanged; acc is never -0 in a +0-seeded add chain).
//  - v_pk_fma_f32 = two independent IEEE RN fmas -> exact, same chain.
//  - recurrences: __fadd_rn(__fmul_rn(beta,state),h) (np mul-then-add).
//  - layer2/mem2: order-free (tanh input, tol 2e-2 >> 1e-6 noise).
// Codegen lessons:
//  r7/r8: 15-way branches (or asm-in-branches) on 60 live accs => scratch
//         spills (WRITE 16MB->10GB). r6 proved a 2-way UNIFORM diamond is
//         safe (VGPR 48, no spills).
//  r10:   launch_bounds(256,8) => 32-VGPR cap => total spill. Need (256,4).
//  r9-r12: no portable pattern selects v_pk_fma_f32; ~115 VALU/entry with
//         scalarized fma + marshaling. => inline-asm pk_fma, straight-line.
// Round-13: asm v_pk_fma_f32 bodies + full/sparse 2-way uniform split.

typedef unsigned int u32;
typedef unsigned short u16;
typedef unsigned long long u64;
typedef __attribute__((ext_vector_type(2))) float f32x2;

// ---- K1: h0 = inputs @ W0 (f32 fma chain) + fused mem0 recurrence -> s0bR ----
__global__ __launch_bounds__(256) void h0_kernel(
    const float* __restrict__ in, const float* __restrict__ W0,
    u16* __restrict__ s0bR) {
    __shared__ float Ls[32 * 512];
    int tid = threadIdx.x;
    int j = blockIdx.x * 256 + tid;
    int r0 = blockIdx.y * 32;
#pragma unroll
    for (int i = 0; i < 64; ++i) {
        int e = i * 256 + tid;
        Ls[e] = in[(size_t)(r0 + (e >> 9)) * 512 + (e & 511)];
    }
    __syncthreads();
    float acc[32];
#pragma unroll
    for (int r = 0; r < 32; ++r) acc[r] = 0.f;
    for (int k = 0; k < 512; ++k) {
        float w = W0[(size_t)k * 2048 + j];
#pragma unroll
        for (int r = 0; r < 32; ++r)
            acc[r] = __fmaf_rn(Ls[r * 512 + k], w, acc[r]);
    }
#pragma unroll
    for (int r = 0; r < 32; ++r) {
        float h = acc[r], mem = 0.f;
        u32 bits = 0;
#pragma unroll
        for (int t = 0; t < 15; ++t) {
            float nm = __fadd_rn(__fmul_rn(0.85f, mem), h);  // np: mul, then add
            bool sp = nm > 1.0f;
            bits |= (sp ? 1u : 0u) << t;
            mem = sp ? 0.f : nm;
        }
        s0bR[(size_t)(r0 + r) * 2048 + j] = (u16)bits;
    }
}

// ---- K1b: per-row active-k compaction (k-ascending preserved) ----
__global__ __launch_bounds__(256) void compact_kernel(
    const u16* __restrict__ s0bR, u32* __restrict__ list,
    int* __restrict__ ccnt) {
    int wv = threadIdx.x >> 6, lane = threadIdx.x & 63;
    int row = blockIdx.x * 4 + wv;
    const u16* mrow = s0bR + (size_t)row * 2048;
    u32* lrow = list + (size_t)row * 2048;
    int base = 0;
    for (int c = 0; c < 32; ++c) {
        int k = c * 64 + lane;
        u32 m = mrow[k];
        bool act = m != 0u;
        u64 b = __ballot(act ? 1 : 0);
        int pre = __popcll(b & ((1ull << lane) - 1ull));
        if (act) lrow[base + pre] = ((u32)k << 16) | m;
        base += __popcll(b);
    }
    int padded = (base + 3) & ~3;
    if (lane < (padded - base)) lrow[base + lane] = 0u;   // mask=0 -> no-op
    if (lane == 0) ccnt[row] = padded;
}

// ---- K2: FUSED h1 (15 steps) over ACTIVE k only + recurrence -> s1b ----
// Wave: 1 row x 256 cols (lane: 4 cols = 2 f32x2 pairs). Block: 4 rows.
// grid 8192: jb = id&7 (XCD-affine W1 slice), rblk = id>>3.
// Per entry: uniform 2-way split (full mask vs sparse), pk_fma bodies.
__global__ __launch_bounds__(256, 4) void h1_fused9(
    const float* __restrict__ W1, const u32* __restrict__ list,
    const int* __restrict__ ccnt, u16* __restrict__ s1b) {
    int id = blockIdx.x;
    int jb = id & 7, rblk = id >> 3;
    int lane = threadIdx.x & 63, wv = threadIdx.x >> 6;
    int row = rblk * 4 + wv;
    int j0 = jb * 256 + lane * 4;
    const float* wp = W1 + j0;
    const u32* lp = list + (size_t)row * 2048;
    int cnt = ccnt[row];                      // padded to multiple of 4 (>=2)

    f32x2 acc[15][2];
#pragma unroll
    for (int t = 0; t < 15; ++t) {
        acc[t][0] = (f32x2){0.f, 0.f};
        acc[t][1] = (f32x2){0.f, 0.f};
    }
    const f32x2 one2 = {1.0f, 1.0f};

#define BODY(MASKV, W01, W23)                                         \
    if ((MASKV) == 0x7FFFu) {          /* all 15 steps spike */       \
        _Pragma("unroll")                                             \
        for (int t = 0; t < 15; ++t) {                                \
            asm("v_pk_fma_f32 %0, %1, %2, %0"                         \
                : "+v"(acc[t][0]) : "v"(one2), "v"(W01));             \
            asm("v_pk_fma_f32 %0, %1, %2, %0"                         \
                : "+v"(acc[t][1]) : "v"(one2), "v"(W23));             \
        }                                                             \
    } else {                                                          \
        _Pragma("unroll")                                             \
        for (int t = 0; t < 15; ++t) {                                \
            float b_ = ((MASKV) & (1u << t)) ? 1.0f : 0.0f;           \
            f32x2 b2_ = {b_, b_};                                     \
            asm("v_pk_fma_f32 %0, %1, %2, %0"                         \
                : "+v"(acc[t][0]) : "v"(b2_), "v"(W01));              \
            asm("v_pk_fma_f32 %0, %1, %2, %0"                         \
                : "+v"(acc[t][1]) : "v"(b2_), "v"(W23));              \
        }                                                             \
    }

    for (int i = 0; i < cnt; i += 2) {
        uint2 e = *(const uint2*)(lp + i);    // 2 entries, uniform addr
        u32 e0 = __builtin_amdgcn_readfirstlane(e.x);
        u32 e1 = __builtin_amdgcn_readfirstlane(e.y);
        u32 m0 = e0 & 0x7FFFu, m1 = e1 & 0x7FFFu;
        const float* p0 = wp + ((size_t)(e0 >> 16) << 11);
        const float* p1 = wp + ((size_t)(e1 >> 16) << 11);
        // preload both entries' w (latency overlap before the branches)
        f32x2 w01a = *(const f32x2*)(p0);
        f32x2 w23a = *(const f32x2*)(p0 + 2);
        f32x2 w01b = *(const f32x2*)(p1);
        f32x2 w23b = *(const f32x2*)(p1 + 2);
        BODY(m0, w01a, w23a);
        BODY(m1, w01b, w23b);
    }
#undef BODY

    // layer-1 recurrence per element (np rounding order) -> s1 bitmasks
    u16 ob[4];
#pragma unroll
    for (int q = 0; q < 4; ++q) {
        float syn = 0.f, mem = 0.f;
        u32 obits = 0;
#pragma unroll
        for (int t = 0; t < 15; ++t) {
            float h1 = acc[t][q >> 1][q & 1];   // static indices after unroll
            float ns = __fadd_rn(__fmul_rn(0.9f, syn), h1);
            float nm = __fadd_rn(__fmul_rn(0.85f, mem), ns);
            bool sp = nm > 1.0f;
            obits |= (sp ? 1u : 0u) << t;
            syn = ns;
            mem = sp ? 0.f : nm;
        }
        ob[q] = (u16)obits;
    }
    uint2 pk;
    pk.x = (u32)ob[0] | ((u32)ob[1] << 16);
    pk.y = (u32)ob[2] | ((u32)ob[3] << 16);
    *(uint2*)(s1b + (size_t)row * 2048 + j0) = pk;
}

// ---- K3: out = tanh(sum_t s1_t @ W2) (order-free reduction) ----
__global__ __launch_bounds__(256) void out_kernel(
    const u16* __restrict__ s1b, const float* __restrict__ W2,
    float* __restrict__ out) {
    __shared__ float P[4][15][8];
    int row = blockIdx.x;
    int tid = threadIdx.x, lane = tid & 63, wv = tid >> 6;
    const u16* srow = s1b + (size_t)row * 2048;
    union { uint4 v; u16 m[8]; } u;
    u.v = *(const uint4*)(srow + tid * 8);
#pragma unroll
    for (int t = 0; t < 15; ++t) {
        float a[8];
#pragma unroll
        for (int jj = 0; jj < 8; ++jj) a[jj] = 0.f;
#pragma unroll
        for (int kk = 0; kk < 8; ++kk) {
            const float* wr = W2 + (size_t)(tid * 8 + kk) * 8;
            if ((u.m[kk] >> t) & 1u) {
#pragma unroll
                for (int jj = 0; jj < 8; ++jj)
                    a[jj] = __fadd_rn(a[jj], wr[jj]);
            }
        }
#pragma unroll
        for (int jj = 0; jj < 8; ++jj) {
            float v = a[jj];
#pragma unroll
            for (int m = 1; m < 64; m <<= 1) v += __shfl_xor(v, m, 64);
            a[jj] = v;
        }
        if (lane == 0) {
#pragma unroll
            for (int jj = 0; jj < 8; ++jj) P[wv][t][jj] = a[jj];
        }
    }
    __syncthreads();
    if (tid < 8) {
        float m2 = 0.f;
#pragma unroll
        for (int t = 0; t < 15; ++t) {
            float s = __fadd_rn(__fadd_rn(P[0][t][tid], P[1][t][tid]),
                                __fadd_rn(P[2][t][tid], P[3][t][tid]));
            m2 = __fadd_rn(m2, s);
        }
        out[(size_t)row * 8 + tid] = tanhf(m2);
    }
}

extern "C" void kernel_launch(void* const* d_in, const int* in_sizes, int n_in,
                              void* d_out, int out_size, void* d_ws, size_t ws_size,
                              hipStream_t stream) {
    const float* inp = (const float*)d_in[0];
    const float* W0  = (const float*)d_in[1];
    const float* W1  = (const float*)d_in[2];
    const float* W2  = (const float*)d_in[3];
    float* out = (float*)d_out;
    char* ws = (char*)d_ws;

    u16* s0bR = (u16*)(ws + 0);            // 16,777,216  [row][k] 15-bit masks
    u16* s1b  = (u16*)(ws + 16777216);     // 16,777,216  [row][j] 15-bit masks
    u32* list = (u32*)(ws + 33554432);     // 33,554,432  [row][2048] (k<<16|mask)
    int* ccnt = (int*)(ws + 67108864);     //     16,384  padded counts
    if (ws_size < 67125248) return;        // ~64 MB scratch

    h0_kernel<<<dim3(8, 128), 256, 0, stream>>>(inp, W0, s0bR);
    compact_kernel<<<1024, 256, 0, stream>>>(s0bR, list, ccnt);
    h1_fused9<<<8192, 256, 0, stream>>>(W1, list, ccnt, s1b);
    out_kernel<<<4096, 256, 0, stream>>>(s1b, W2, out);
}

// Round 14
// 3968.501 us; speedup vs baseline: 2.8651x; 2.8651x over previous
//
#include <hip/hip_runtime.h>
#include <math.h>

// TD3ActorDSNN — f32 class-faithful, fused, round 14.
// Exactness invariants (validated r4-r6, r9, r11-r13):
//  - per-element k-ascending single-accumulator f32 chains for h0 and h1;
//    skipping k with mask==0 is bit-identical; order never changes.
//  - b in {0,1}: fma(b,w,acc) EXACT (b=1 -> RN(acc+w) == validated add;
//    b=0 -> acc unchanged; acc never -0 in a +0-seeded add chain).
//  - recurrences: __fadd_rn(__fmul_rn(beta,state),h) (np mul-then-add).
//  - layer2/mem2: order-free (tanh input, tol 2e-2 >> 1e-6 noise).
// Codegen lessons (hard-won):
//  r7/r8/r13: branches or asm-tied operands touching the 60 live accs =>
//         scratch spills (WRITE 16MB -> 0.8-10GB). ONLY safe shape:
//         single straight-line portable body, no asm, no multi-way CF.
//  r10:   launch_bounds(256,8) => 32-VGPR cap => total spill. Need (256,4).
//  r9-r12: vector types (f32x2) forced per-lane b materialization +
//         marshaling (~115 VALU/entry vs 60 needed).
// Round-14: pure scalar body. mask is SGPR (readfirstlane); b is a uniform
// bit-cast select => SALU s_bitcmp+s_cselect; v_fmac_f32 takes SGPR src0.
// Expect ~66 VALU/entry.

typedef unsigned int u32;
typedef unsigned short u16;
typedef unsigned long long u64;

// ---- K1: h0 = inputs @ W0 (f32 fma chain) + fused mem0 recurrence -> s0bR ----
__global__ __launch_bounds__(256) void h0_kernel(
    const float* __restrict__ in, const float* __restrict__ W0,
    u16* __restrict__ s0bR) {
    __shared__ float Ls[32 * 512];
    int tid = threadIdx.x;
    int j = blockIdx.x * 256 + tid;
    int r0 = blockIdx.y * 32;
#pragma unroll
    for (int i = 0; i < 64; ++i) {
        int e = i * 256 + tid;
        Ls[e] = in[(size_t)(r0 + (e >> 9)) * 512 + (e & 511)];
    }
    __syncthreads();
    float acc[32];
#pragma unroll
    for (int r = 0; r < 32; ++r) acc[r] = 0.f;
    for (int k = 0; k < 512; ++k) {
        float w = W0[(size_t)k * 2048 + j];
#pragma unroll
        for (int r = 0; r < 32; ++r)
            acc[r] = __fmaf_rn(Ls[r * 512 + k], w, acc[r]);
    }
#pragma unroll
    for (int r = 0; r < 32; ++r) {
        float h = acc[r], mem = 0.f;
        u32 bits = 0;
#pragma unroll
        for (int t = 0; t < 15; ++t) {
            float nm = __fadd_rn(__fmul_rn(0.85f, mem), h);  // np: mul, then add
            bool sp = nm > 1.0f;
            bits |= (sp ? 1u : 0u) << t;
            mem = sp ? 0.f : nm;
        }
        s0bR[(size_t)(r0 + r) * 2048 + j] = (u16)bits;
    }
}

// ---- K1b: per-row active-k compaction (k-ascending preserved) ----
__global__ __launch_bounds__(256) void compact_kernel(
    const u16* __restrict__ s0bR, u32* __restrict__ list,
    int* __restrict__ ccnt) {
    int wv = threadIdx.x >> 6, lane = threadIdx.x & 63;
    int row = blockIdx.x * 4 + wv;
    const u16* mrow = s0bR + (size_t)row * 2048;
    u32* lrow = list + (size_t)row * 2048;
    int base = 0;
    for (int c = 0; c < 32; ++c) {
        int k = c * 64 + lane;
        u32 m = mrow[k];
        bool act = m != 0u;
        u64 b = __ballot(act ? 1 : 0);
        int pre = __popcll(b & ((1ull << lane) - 1ull));
        if (act) lrow[base + pre] = ((u32)k << 16) | m;
        base += __popcll(b);
    }
    int padded = (base + 1) & ~1;
    if (lane < (padded - base)) lrow[base + lane] = 0u;   // mask=0 -> no-op
    if (lane == 0) ccnt[row] = padded;
}

// ---- K2: FUSED h1 (15 steps) over ACTIVE k only + recurrence -> s1b ----
// Wave: 1 row x 256 cols (lane: 4 cols). Block: 4 rows. grid 8192:
// jb = id&7 (XCD-affine W1 slice), rblk = id>>3.
// Single straight-line body; b = uniform SALU select; scalar v_fmac.
__global__ __launch_bounds__(256, 4) void h1_fused10(
    const float* __restrict__ W1, const u32* __restrict__ list,
    const int* __restrict__ ccnt, u16* __restrict__ s1b) {
    int id = blockIdx.x;
    int jb = id & 7, rblk = id >> 3;
    int lane = threadIdx.x & 63, wv = threadIdx.x >> 6;
    int row = rblk * 4 + wv;
    int j0 = jb * 256 + lane * 4;
    const float* wp = W1 + j0;
    const u32* lp = list + (size_t)row * 2048;
    int cnt = ccnt[row];                      // padded to multiple of 2

    float a0[15], a1[15], a2[15], a3[15];
#pragma unroll
    for (int t = 0; t < 15; ++t) { a0[t] = 0.f; a1[t] = 0.f; a2[t] = 0.f; a3[t] = 0.f; }

    for (int i = 0; i < cnt; i += 2) {
        uint2 e = *(const uint2*)(lp + i);    // 2 entries, wave-uniform addr
        u32 e0 = __builtin_amdgcn_readfirstlane(e.x);   // SGPR: k<<16 | mask
        u32 e1 = __builtin_amdgcn_readfirstlane(e.y);
        // both w loads issued up front (latency overlap)
        float4 w0 = *(const float4*)(wp + ((size_t)(e0 >> 16) << 11));
        float4 w1 = *(const float4*)(wp + ((size_t)(e1 >> 16) << 11));
#pragma unroll
        for (int t = 0; t < 15; ++t) {
            // uniform select -> s_bitcmp + s_cselect (SALU); b stays in SGPR
            float b = __builtin_bit_cast(float, (e0 & (1u << t)) ? 0x3F800000u : 0u);
            a0[t] = __fmaf_rn(b, w0.x, a0[t]);   // v_fmac_f32 acc, s, v
            a1[t] = __fmaf_rn(b, w0.y, a1[t]);
            a2[t] = __fmaf_rn(b, w0.z, a2[t]);
            a3[t] = __fmaf_rn(b, w0.w, a3[t]);
        }
#pragma unroll
        for (int t = 0; t < 15; ++t) {
            float b = __builtin_bit_cast(float, (e1 & (1u << t)) ? 0x3F800000u : 0u);
            a0[t] = __fmaf_rn(b, w1.x, a0[t]);
            a1[t] = __fmaf_rn(b, w1.y, a1[t]);
            a2[t] = __fmaf_rn(b, w1.z, a2[t]);
            a3[t] = __fmaf_rn(b, w1.w, a3[t]);
        }
    }

    // layer-1 recurrence per element (np rounding order) -> s1 bitmasks
    auto rec = [](const float* a) -> u16 {
        float syn = 0.f, mem = 0.f;
        u32 obits = 0;
#pragma unroll
        for (int t = 0; t < 15; ++t) {
            float ns = __fadd_rn(__fmul_rn(0.9f, syn), a[t]);
            float nm = __fadd_rn(__fmul_rn(0.85f, mem), ns);
            bool sp = nm > 1.0f;
            obits |= (sp ? 1u : 0u) << t;
            syn = ns;
            mem = sp ? 0.f : nm;
        }
        return (u16)obits;
    };
    u16 ob0 = rec(a0), ob1 = rec(a1), ob2 = rec(a2), ob3 = rec(a3);
    uint2 pk;
    pk.x = (u32)ob0 | ((u32)ob1 << 16);
    pk.y = (u32)ob2 | ((u32)ob3 << 16);
    *(uint2*)(s1b + (size_t)row * 2048 + j0) = pk;
}

// ---- K3: out = tanh(sum_t s1_t @ W2) (order-free reduction) ----
__global__ __launch_bounds__(256) void out_kernel(
    const u16* __restrict__ s1b, const float* __restrict__ W2,
    float* __restrict__ out) {
    __shared__ float P[4][15][8];
    int row = blockIdx.x;
    int tid = threadIdx.x, lane = tid & 63, wv = tid >> 6;
    const u16* srow = s1b + (size_t)row * 2048;
    union { uint4 v; u16 m[8]; } u;
    u.v = *(const uint4*)(srow + tid * 8);
#pragma unroll
    for (int t = 0; t < 15; ++t) {
        float a[8];
#pragma unroll
        for (int jj = 0; jj < 8; ++jj) a[jj] = 0.f;
#pragma unroll
        for (int kk = 0; kk < 8; ++kk) {
            const float* wr = W2 + (size_t)(tid * 8 + kk) * 8;
            if ((u.m[kk] >> t) & 1u) {
#pragma unroll
                for (int jj = 0; jj < 8; ++jj)
                    a[jj] = __fadd_rn(a[jj], wr[jj]);
            }
        }
#pragma unroll
        for (int jj = 0; jj < 8; ++jj) {
            float v = a[jj];
#pragma unroll
            for (int m = 1; m < 64; m <<= 1) v += __shfl_xor(v, m, 64);
            a[jj] = v;
        }
        if (lane == 0) {
#pragma unroll
            for (int jj = 0; jj < 8; ++jj) P[wv][t][jj] = a[jj];
        }
    }
    __syncthreads();
    if (tid < 8) {
        float m2 = 0.f;
#pragma unroll
        for (int t = 0; t < 15; ++t) {
            float s = __fadd_rn(__fadd_rn(P[0][t][tid], P[1][t][tid]),
                                __fadd_rn(P[2][t][tid], P[3][t][tid]));
            m2 = __fadd_rn(m2, s);
        }
        out[(size_t)row * 8 + tid] = tanhf(m2);
    }
}

extern "C" void kernel_launch(void* const* d_in, const int* in_sizes, int n_in,
                              void* d_out, int out_size, void* d_ws, size_t ws_size,
                              hipStream_t stream) {
    const float* inp = (const float*)d_in[0];
    const float* W0  = (const float*)d_in[1];
    const float* W1  = (const float*)d_in[2];
    const float* W2  = (const float*)d_in[3];
    float* out = (float*)d_out;
    char* ws = (char*)d_ws;

    u16* s0bR = (u16*)(ws + 0);            // 16,777,216  [row][k] 15-bit masks
    u16* s1b  = (u16*)(ws + 16777216);     // 16,777,216  [row][j] 15-bit masks
    u32* list = (u32*)(ws + 33554432);     // 33,554,432  [row][2048] (k<<16|mask)
    int* ccnt = (int*)(ws + 67108864);     //     16,384  padded counts
    if (ws_size < 67125248) return;        // ~64 MB scratch

    h0_kernel<<<dim3(8, 128), 256, 0, stream>>>(inp, W0, s0bR);
    compact_kernel<<<1024, 256, 0, stream>>>(s0bR, list, ccnt);
    h1_fused10<<<8192, 256, 0, stream>>>(W1, list, ccnt, s1b);
    out_kernel<<<4096, 256, 0, stream>>>(s1b, W2, out);
}